// Round 7
// baseline (136.479 us; speedup 1.0000x reference)
//
#include <hip/hip_runtime.h>
#include <math.h>

#define NG (64*64*64)
#define NBLK 256

typedef __bf16 v8bf __attribute__((ext_vector_type(8)));
typedef float  v4f  __attribute__((ext_vector_type(4)));

// ---- workspace layout (bytes) ----
#define WS_W    0                        // float2[NG]  2 MiB (W2[kz][x][y])
#define WS_EZH  (2*1024*1024)            // bf16[64][768]  EzT hi (row=z, col=j)
#define WS_EZL  (WS_EZH + 64*768*2)      // bf16[64][768]  EzT lo
#define WS_PART (WS_EZL + 64*768*2)      // double[65]: [0..63] plane |G|^2, [64] DC
#define WS_BAR  (WS_PART + 1024)         // int[4]: grid-barrier state (memset/launch)

// ---------------------------------------------------------------------------
// Software grid barrier (sense via generation counter). State memset to 0
// before each launch. Device-scope atomics carry acquire/release (L2 wb/inv
// on gfx950), so cross-XCD data written before the barrier is visible after.
// ---------------------------------------------------------------------------
__device__ __forceinline__ void gbar(int* cnt, int* gen)
{
    __syncthreads();                       // all block threads done (vmcnt drained)
    if (threadIdx.x == 0) {
        int g = __hip_atomic_load(gen, __ATOMIC_RELAXED, __HIP_MEMORY_SCOPE_AGENT);
        if (__hip_atomic_fetch_add(cnt, 1, __ATOMIC_ACQ_REL,
                                   __HIP_MEMORY_SCOPE_AGENT) == NBLK - 1) {
            __hip_atomic_store(cnt, 0, __ATOMIC_RELAXED, __HIP_MEMORY_SCOPE_AGENT);
            __hip_atomic_fetch_add(gen, 1, __ATOMIC_ACQ_REL,
                                   __HIP_MEMORY_SCOPE_AGENT);
        } else {
            while (__hip_atomic_load(gen, __ATOMIC_ACQUIRE,
                                     __HIP_MEMORY_SCOPE_AGENT) == g)
                __builtin_amdgcn_s_sleep(1);
        }
    }
    __syncthreads();
}

// ---------------------------------------------------------------------------
// Fast radix-2 8-point FFT, natural order in/out. CONJ=true -> inverse sign.
// ---------------------------------------------------------------------------
__device__ __forceinline__ float2 cadd(float2 a, float2 b) {
    return make_float2(a.x + b.x, a.y + b.y);
}
__device__ __forceinline__ float2 csub(float2 a, float2 b) {
    return make_float2(a.x - b.x, a.y - b.y);
}
template <bool CONJ>
__device__ __forceinline__ float2 mulmi(float2 a) {   // *(-i) fwd, *(+i) inv
    return CONJ ? make_float2(-a.y, a.x) : make_float2(a.y, -a.x);
}

template <bool CONJ>
__device__ __forceinline__ void fft8(const float2 x[8], float2 y[8])
{
    const float r = 0.70710678118654752f;
    float2 ee0 = cadd(x[0], x[4]), ee1 = csub(x[0], x[4]);
    float2 eo0 = cadd(x[2], x[6]), eo1 = csub(x[2], x[6]);
    float2 E0 = cadd(ee0, eo0), E2 = csub(ee0, eo0);
    float2 me = mulmi<CONJ>(eo1);
    float2 E1 = cadd(ee1, me), E3 = csub(ee1, me);
    float2 oe0 = cadd(x[1], x[5]), oe1 = csub(x[1], x[5]);
    float2 oo0 = cadd(x[3], x[7]), oo1 = csub(x[3], x[7]);
    float2 O0 = cadd(oe0, oo0), O2 = csub(oe0, oo0);
    float2 mo = mulmi<CONJ>(oo1);
    float2 O1 = cadd(oe1, mo), O3 = csub(oe1, mo);
    float2 W1O1 = CONJ ? make_float2(r * (O1.x - O1.y), r * (O1.x + O1.y))
                       : make_float2(r * (O1.x + O1.y), r * (O1.y - O1.x));
    float2 W2O2 = mulmi<CONJ>(O2);
    float2 W3O3 = CONJ ? make_float2(-r * (O3.x + O3.y), r * (O3.x - O3.y))
                       : make_float2(r * (O3.y - O3.x), -r * (O3.x + O3.y));
    y[0] = cadd(E0, O0);   y[4] = csub(E0, O0);
    y[1] = cadd(E1, W1O1); y[5] = csub(E1, W1O1);
    y[2] = cadd(E2, W2O2); y[6] = csub(E2, W2O2);
    y[3] = cadd(E3, W3O3); y[7] = csub(E3, W3O3);
}

// 64-pt transform, radix 8x8, 8 threads/line. Input xin[n2] = element 8*n2+t.
// L[(...)*es] per-line exchange buffer (each thread rewrites the slots it
// read -> no pre-barrier). Internal block barrier; ALL threads must call
// (inactive skip compute). Output y[k2] = element t+8*k2.
template <bool CONJ>
__device__ __forceinline__ void xf64(const float2 xin[8], float2* L, int es,
                                     int t, const float2* tw, float2 y[8],
                                     bool active)
{
    float2 b[8];
    if (active) {
        fft8<CONJ>(xin, b);
#pragma unroll
        for (int k1 = 0; k1 < 8; ++k1) {
            float2 wv = tw[(t * k1) & 63];
            float ws = CONJ ? -wv.y : wv.y;
            float tr = b[k1].x * wv.x - b[k1].y * ws;
            float ti = b[k1].x * ws + b[k1].y * wv.x;
            b[k1] = make_float2(tr, ti);
        }
#pragma unroll
        for (int k1 = 0; k1 < 8; ++k1)
            L[(k1 * 8 + t) * es] = b[k1];
    }
    __syncthreads();
    if (active) {
        float2 a[8];
#pragma unroll
        for (int n1 = 0; n1 < 8; ++n1) a[n1] = L[(t * 8 + n1) * es];
        fft8<CONJ>(a, y);
    }
}

// ---------------------------------------------------------------------------
// Fully fused pipeline: P0 EzT+twiddles | P1 density(MFMA)+fwd-z | P2 plane
// (fwd-y/x + Hamming + Parseval + inv-x/y) | P3 inv-z + normalize.
// 256 blocks x 512 threads, grid barriers between phases.
// ---------------------------------------------------------------------------
__global__ __launch_bounds__(512) void fused_kernel(
    const float* __restrict__ X, const float* __restrict__ aw,
    const float* __restrict__ bw, const float* __restrict__ ham,
    __bf16* __restrict__ EzTh, __bf16* __restrict__ EzTl,
    double* __restrict__ partial, float2* __restrict__ W2,
    float* __restrict__ outr, int* __restrict__ bar)
{
    __shared__ __align__(16) char SMEM[58112];
    __shared__ float2 tw[64];
    __shared__ double red[8];
    __shared__ float nrm[2];

    int tid = threadIdx.x;
    int blk = blockIdx.x;

    // ================= P0: twiddles (per block) + EzT =================
    if (tid < 64) {
        float ang = -6.28318530717958647692f * (float)tid / 64.0f;
        float s, c;
        sincosf(ang, &s, &c);
        tw[tid] = make_float2(c, s);
    }
    if (blk < 64) {
        float pc = 0.5f * (float)blk;
        for (int j = tid; j < 768; j += 512) {
            int a = j / 6;
            float dz = pc - X[3 * a + 2];
            float ez = __expf(bw[j] * dz * dz);
            __bf16 h = (__bf16)ez;
            EzTh[blk * 768 + j] = h;
            EzTl[blk * 768 + j] = (__bf16)(ez - (float)h);
        }
    }
    gbar(bar, bar + 1);

    // ================= P1: density (MFMA, K-split) + fwd z-FFT ========
    {
        auto Ah = (__bf16(*)[776])(SMEM);
        auto Al = (__bf16(*)[776])(SMEM + 24832);
        auto D  = (float2(*)[66])(SMEM + 49664);
        int x = blk >> 2, yq = blk & 3;
        float px = 0.5f * (float)x;

        // A[y][j] = aw[j]*exp(bw[j]*(dx^2+dy^2)), hi/lo bf16, in-register
        {
            int row = tid >> 5;                 // 0..15
            int a0 = (tid & 31) * 4;            // 4 atoms -> 24 consecutive j
            float py = 0.5f * (float)(yq * 16 + row);
#pragma unroll
            for (int ai = 0; ai < 4; ++ai) {
                int a = a0 + ai;
                float dxa = px - X[3 * a + 0];
                float dya = py - X[3 * a + 1];
                float d2 = dxa * dxa + dya * dya;
                int jb = a * 6;
#pragma unroll
                for (int p = 0; p < 3; ++p) {
                    int j = jb + 2 * p;
                    float e0 = aw[j] * __expf(bw[j] * d2);
                    float e1 = aw[j + 1] * __expf(bw[j + 1] * d2);
                    __bf16 h0 = (__bf16)e0, h1 = (__bf16)e1;
                    __bf16 l0 = (__bf16)(e0 - (float)h0);
                    __bf16 l1 = (__bf16)(e1 - (float)h1);
                    unsigned hp = ((unsigned)__builtin_bit_cast(unsigned short, h1) << 16)
                                | (unsigned)__builtin_bit_cast(unsigned short, h0);
                    unsigned lp = ((unsigned)__builtin_bit_cast(unsigned short, l1) << 16)
                                | (unsigned)__builtin_bit_cast(unsigned short, l0);
                    *(unsigned*)&Ah[row][j] = hp;
                    *(unsigned*)&Al[row][j] = lp;
                }
            }
        }
        __syncthreads();

        // GEMM: wave w -> z-tile (w&3), k-half (w>>2)
        {
            int w = tid >> 6;
            int l = tid & 63;
            int m = l & 15;
            int g = l >> 4;
            int zt = w & 3;
            int kh = w >> 2;
            v4f accHH = {0.f, 0.f, 0.f, 0.f};
            v4f accHL = {0.f, 0.f, 0.f, 0.f};
            v4f accLH = {0.f, 0.f, 0.f, 0.f};
            const __bf16* bhp = EzTh + (zt * 16 + m) * 768 + kh * 384 + g * 8;
            const __bf16* blp = EzTl + (zt * 16 + m) * 768 + kh * 384 + g * 8;
            const __bf16* ahp = &Ah[m][kh * 384 + g * 8];
            const __bf16* alp = &Al[m][kh * 384 + g * 8];
#pragma unroll 4
            for (int ks = 0; ks < 12; ++ks) {
                v8bf aH = *(const v8bf*)(ahp + ks * 32);
                v8bf aL = *(const v8bf*)(alp + ks * 32);
                v8bf bH = *(const v8bf*)(bhp + ks * 32);
                v8bf bL = *(const v8bf*)(blp + ks * 32);
                accHH = __builtin_amdgcn_mfma_f32_16x16x32_bf16(aH, bH, accHH, 0, 0, 0);
                accHL = __builtin_amdgcn_mfma_f32_16x16x32_bf16(aH, bL, accHL, 0, 0, 0);
                accLH = __builtin_amdgcn_mfma_f32_16x16x32_bf16(aL, bH, accLH, 0, 0, 0);
            }
            // C layout: col = lane&15, row = (lane>>4)*4 + reg  [m89-verified]
#pragma unroll
            for (int r = 0; r < 4; ++r) {
                float s = accHH[r] + accHL[r] + accLH[r];
                if (kh == 0) D[g * 4 + r][zt * 16 + m].x = s;
                else         D[g * 4 + r][zt * 16 + m].y = s;
            }
        }
        __syncthreads();

        // forward z-FFT on the 16 lines (128 active threads)
        bool active = tid < 128;
        int lid = (tid >> 3) & 15, t = tid & 7;
        float2 xin[8], y[8];
        if (active) {
#pragma unroll
            for (int n2 = 0; n2 < 8; ++n2) {
                float2 v = D[lid][8 * n2 + t];
                xin[n2] = make_float2(v.x + v.y, 0.f);   // sum k-halves
            }
        }
        xf64<false>(xin, &D[lid][0], 1, t, tw, y, active);
        if (active) {
            int ybase = yq * 16 + lid;
#pragma unroll
            for (int k2 = 0; k2 < 8; ++k2)
                W2[(t + 8 * k2) * 4096 + x * 64 + ybase] = y[k2];
        }
    }
    gbar(bar, bar + 1);

    // ================= P2: plane (blocks 0..63) =======================
    if (blk < 64) {
        auto P = (float2(*)[66])(SMEM);
        int z0 = blk;
        const float4* src = (const float4*)(W2 + z0 * 4096);
#pragma unroll
        for (int q = 0; q < 4; ++q) {
            int i = tid + q * 512;
            float4 v = src[i];
            int e = i * 2;
            P[e >> 6][e & 63] = make_float2(v.x, v.y);
            P[e >> 6][(e & 63) + 1] = make_float2(v.z, v.w);
        }
        __syncthreads();

        int lid = tid >> 3, t = tid & 7;
        float2 xin[8], y[8];

        // forward y (lines = rows x = lid)
#pragma unroll
        for (int n2 = 0; n2 < 8; ++n2) xin[n2] = P[lid][8 * n2 + t];
        xf64<false>(xin, &P[lid][0], 1, t, tw, y, true);
        __syncthreads();
#pragma unroll
        for (int k2 = 0; k2 < 8; ++k2) P[lid][t + 8 * k2] = y[k2];
        __syncthreads();

        // forward x (lines = columns ky = lid) + Hamming
#pragma unroll
        for (int n2 = 0; n2 < 8; ++n2) xin[n2] = P[8 * n2 + t][lid];
        xf64<false>(xin, &P[0][lid], 66, t, tw, y, true);
        {
            int hyz = ((lid + 32) & 63) * 64 + ((z0 + 32) & 63);
#pragma unroll
            for (int k2 = 0; k2 < 8; ++k2) {
                int kx = t + 8 * k2;
                float h = ham[((kx + 32) & 63) * 4096 + hyz];
                y[k2].x *= h; y[k2].y *= h;
            }
        }
        // Parseval partial over this plane + DC coefficient
        {
            double s2 = 0.0;
#pragma unroll
            for (int k2 = 0; k2 < 8; ++k2)
                s2 += (double)y[k2].x * y[k2].x + (double)y[k2].y * y[k2].y;
#pragma unroll
            for (int off = 32; off > 0; off >>= 1)
                s2 += __shfl_down(s2, off, 64);
            if ((tid & 63) == 0) red[tid >> 6] = s2;
            if (z0 == 0 && tid == 0)
                partial[64] = (double)y[0].x;
        }
        __syncthreads();
#pragma unroll
        for (int k2 = 0; k2 < 8; ++k2) P[t + 8 * k2][lid] = y[k2];
        __syncthreads();
        if (tid == 0) {
            double s = 0.0;
#pragma unroll
            for (int i = 0; i < 8; ++i) s += red[i];
            partial[z0] = s;
        }

        // inverse x
#pragma unroll
        for (int n2 = 0; n2 < 8; ++n2) xin[n2] = P[8 * n2 + t][lid];
        xf64<true>(xin, &P[0][lid], 66, t, tw, y, true);
        __syncthreads();
#pragma unroll
        for (int k2 = 0; k2 < 8; ++k2) P[t + 8 * k2][lid] = y[k2];
        __syncthreads();

        // inverse y, write back
#pragma unroll
        for (int n2 = 0; n2 < 8; ++n2) xin[n2] = P[lid][8 * n2 + t];
        xf64<true>(xin, &P[lid][0], 1, t, tw, y, true);
#pragma unroll
        for (int k2 = 0; k2 < 8; ++k2)
            W2[z0 * 4096 + lid * 64 + t + 8 * k2] = y[k2];
    }
    gbar(bar, bar + 1);

    // ================= P3: inverse z + normalize ======================
    {
        auto ln = (float2(*)[66])(SMEM);
        if (tid < 64) {
            double s = partial[tid];
#pragma unroll
            for (int off = 32; off > 0; off >>= 1)
                s += __shfl_down(s, off, 64);
            if (tid == 0) {
                double mean = partial[64] * (1.0 / 262144.0);
                double var = s * (1.0 / 262144.0 / 262144.0) - mean * mean;
                nrm[0] = (float)mean;
                nrm[1] = (float)(1.0 / (sqrt(var > 0.0 ? var : 0.0) + 1e-8));
            }
        }
        __syncthreads();

        bool active = tid < 128;
        int lid = tid >> 3, t = tid & 7;          // lid 0..15 when active
        int L = blk * 16 + (lid & 15);
        float2 xin[8], y[8];
        if (active) {
#pragma unroll
            for (int n2 = 0; n2 < 8; ++n2)
                xin[n2] = W2[(8 * n2 + t) * 4096 + L];
        }
        xf64<true>(xin, &ln[lid & 15][0], 1, t, tw, y, active);
        if (active) {
            float mean = nrm[0], rstd = nrm[1];
#pragma unroll
            for (int k2 = 0; k2 < 8; ++k2) {
                float v = y[k2].x * (1.0f / 262144.0f);
                outr[L * 64 + t + 8 * k2] = (v - mean) * rstd;
            }
        }
    }
}

// ---------------------------------------------------------------------------
extern "C" void kernel_launch(void* const* d_in, const int* in_sizes, int n_in,
                              void* d_out, int out_size, void* d_ws,
                              size_t ws_size, hipStream_t stream)
{
    const float* X   = (const float*)d_in[0];
    const float* aw  = (const float*)d_in[1];
    const float* bw  = (const float*)d_in[2];
    const float* ham = (const float*)d_in[4];
    float* out = (float*)d_out;

    char* ws = (char*)d_ws;
    float2* W2   = (float2*)(ws + WS_W);
    __bf16* EzTh = (__bf16*)(ws + WS_EZH);
    __bf16* EzTl = (__bf16*)(ws + WS_EZL);
    double* part = (double*)(ws + WS_PART);
    int*    bar  = (int*)(ws + WS_BAR);

    // zero the grid-barrier state (graph-capturable, deterministic per launch)
    hipMemsetAsync(bar, 0, 16, stream);
    fused_kernel<<<NBLK, 512, 0, stream>>>(X, aw, bw, ham, EzTh, EzTl,
                                           part, W2, out, bar);
}

// Round 8
// 31.587 us; speedup vs baseline: 4.3208x; 4.3208x over previous
//
#include <hip/hip_runtime.h>
#include <math.h>

#define NG (64*64*64)

typedef __bf16 v8bf __attribute__((ext_vector_type(8)));
typedef float  v4f  __attribute__((ext_vector_type(4)));

// ---- workspace layout (bytes) ----
#define WS_W    0                        // float2[NG]  2 MiB   (layout W2[kz][x][y])
#define WS_EZH  (2*1024*1024)            // bf16[64][768]  EzT hi (row = z, col = j)
#define WS_EZL  (WS_EZH + 64*768*2)      // bf16[64][768]  EzT lo
#define WS_TW   (WS_EZL + 64*768*2)      // float2[64] forward twiddles
#define WS_PART (WS_TW  + 64*8)          // double[65]: [0..63] plane |G|^2, [64] DC

// Band limit: hamming == 0 exactly for per-axis |k| > 16 (cutoff 0.5 = 16/32).
// In DFT index terms: kz in {0..16} U {48..63} survives; 17..47 is dead.
#define KZ_LIVE(k) ((k) <= 16 || (k) >= 48)

// ---------------------------------------------------------------------------
// K0: EzT (z-axis Gaussian factors, transposed, hi/lo bf16) + twiddles.
// 64 blocks (c = z coord) x 256 threads, 3 j per thread.
// ---------------------------------------------------------------------------
__global__ __launch_bounds__(256) void ez_tw_kernel(
    const float* __restrict__ X, const float* __restrict__ bw,
    __bf16* __restrict__ EzTh, __bf16* __restrict__ EzTl,
    float2* __restrict__ twg)
{
    int tid = threadIdx.x;
    int c = blockIdx.x;
    if (c == 0 && tid < 64) {
        float ang = -6.28318530717958647692f * (float)tid / 64.0f;
        float s, cs;
        sincosf(ang, &s, &cs);
        twg[tid] = make_float2(cs, s);
    }
    float pc = 0.5f * (float)c;
#pragma unroll
    for (int q = 0; q < 3; ++q) {
        int j = q * 256 + tid;              // 0..767
        int a = j / 6;
        float dz = pc - X[3 * a + 2];
        float ez = __expf(bw[j] * dz * dz);
        __bf16 h = (__bf16)ez;
        __bf16 l = (__bf16)(ez - (float)h);
        EzTh[c * 768 + j] = h;
        EzTl[c * 768 + j] = l;
    }
}

// ---------------------------------------------------------------------------
// Fast radix-2 8-point FFT, natural order in/out. CONJ=true -> inverse sign.
// ---------------------------------------------------------------------------
__device__ __forceinline__ float2 cadd(float2 a, float2 b) {
    return make_float2(a.x + b.x, a.y + b.y);
}
__device__ __forceinline__ float2 csub(float2 a, float2 b) {
    return make_float2(a.x - b.x, a.y - b.y);
}
template <bool CONJ>
__device__ __forceinline__ float2 mulmi(float2 a) {   // *(-i) fwd, *(+i) inv
    return CONJ ? make_float2(-a.y, a.x) : make_float2(a.y, -a.x);
}

template <bool CONJ>
__device__ __forceinline__ void fft8(const float2 x[8], float2 y[8])
{
    const float r = 0.70710678118654752f;
    float2 ee0 = cadd(x[0], x[4]), ee1 = csub(x[0], x[4]);
    float2 eo0 = cadd(x[2], x[6]), eo1 = csub(x[2], x[6]);
    float2 E0 = cadd(ee0, eo0), E2 = csub(ee0, eo0);
    float2 me = mulmi<CONJ>(eo1);
    float2 E1 = cadd(ee1, me), E3 = csub(ee1, me);
    float2 oe0 = cadd(x[1], x[5]), oe1 = csub(x[1], x[5]);
    float2 oo0 = cadd(x[3], x[7]), oo1 = csub(x[3], x[7]);
    float2 O0 = cadd(oe0, oo0), O2 = csub(oe0, oo0);
    float2 mo = mulmi<CONJ>(oo1);
    float2 O1 = cadd(oe1, mo), O3 = csub(oe1, mo);
    float2 W1O1 = CONJ ? make_float2(r * (O1.x - O1.y), r * (O1.x + O1.y))
                       : make_float2(r * (O1.x + O1.y), r * (O1.y - O1.x));
    float2 W2O2 = mulmi<CONJ>(O2);
    float2 W3O3 = CONJ ? make_float2(-r * (O3.x + O3.y), r * (O3.x - O3.y))
                       : make_float2(r * (O3.y - O3.x), -r * (O3.x + O3.y));
    y[0] = cadd(E0, O0);   y[4] = csub(E0, O0);
    y[1] = cadd(E1, W1O1); y[5] = csub(E1, W1O1);
    y[2] = cadd(E2, W2O2); y[6] = csub(E2, W2O2);
    y[3] = cadd(E3, W3O3); y[7] = csub(E3, W3O3);
}

// 64-pt transform, radix 8x8, 8 threads/line. Input xin[n2] = element 8*n2+t.
// L[(...)*es] is the per-line exchange buffer (each thread rewrites the slots
// it read -> no pre-barrier). Internal block barrier; ALL threads must call
// (inactive skip compute). Output y[k2] = element t+8*k2.
template <bool CONJ>
__device__ __forceinline__ void xf64(const float2 xin[8], float2* L, int es,
                                     int t, const float2* tw, float2 y[8],
                                     bool active)
{
    float2 b[8];
    if (active) {
        fft8<CONJ>(xin, b);
#pragma unroll
        for (int k1 = 0; k1 < 8; ++k1) {
            float2 wv = tw[(t * k1) & 63];
            float ws = CONJ ? -wv.y : wv.y;
            float tr = b[k1].x * wv.x - b[k1].y * ws;
            float ti = b[k1].x * ws + b[k1].y * wv.x;
            b[k1] = make_float2(tr, ti);
        }
#pragma unroll
        for (int k1 = 0; k1 < 8; ++k1)
            L[(k1 * 8 + t) * es] = b[k1];
    }
    __syncthreads();
    if (active) {
        float2 a[8];
#pragma unroll
        for (int n1 = 0; n1 < 8; ++n1) a[n1] = L[(t * 8 + n1) * es];
        fft8<CONJ>(a, y);
    }
}

// ---------------------------------------------------------------------------
// K1: density (A computed in-register, MFMA, K-split over 8 waves) + fwd z-FFT.
// Block = (x, y-quarter), 512 threads, 256 blocks. Writes only in-band kz.
// ---------------------------------------------------------------------------
__global__ __launch_bounds__(512) void density_fftz_kernel(
    const float* __restrict__ X, const float* __restrict__ aw,
    const float* __restrict__ bw, const __bf16* __restrict__ EzTh,
    const __bf16* __restrict__ EzTl, const float2* __restrict__ twg,
    float2* __restrict__ W2)
{
    __shared__ __align__(16) __bf16 Ah[16][776];
    __shared__ __align__(16) __bf16 Al[16][776];
    __shared__ float2 D[16][66];
    __shared__ float2 tw[64];

    int tid = threadIdx.x;
    if (tid < 64) tw[tid] = twg[tid];

    int blk = blockIdx.x;
    int x  = blk >> 2;
    int yq = blk & 3;
    float px = 0.5f * (float)x;

    // ---- build A in-register: thread -> (row, 4 atoms x 6 terms) ----
    {
        int row = tid >> 5;                 // 0..15
        int a0  = (tid & 31) * 4;           // 4 atoms -> 24 consecutive j
        float py = 0.5f * (float)(yq * 16 + row);
#pragma unroll
        for (int ai = 0; ai < 4; ++ai) {
            int a = a0 + ai;
            float dxa = px - X[3 * a + 0];
            float dya = py - X[3 * a + 1];
            float d2 = dxa * dxa + dya * dya;
            int jb = a * 6;
#pragma unroll
            for (int p = 0; p < 3; ++p) {   // 3 packed pairs
                int j = jb + 2 * p;
                float e0 = aw[j] * __expf(bw[j] * d2);
                float e1 = aw[j + 1] * __expf(bw[j + 1] * d2);
                __bf16 h0 = (__bf16)e0, h1 = (__bf16)e1;
                __bf16 l0 = (__bf16)(e0 - (float)h0);
                __bf16 l1 = (__bf16)(e1 - (float)h1);
                unsigned hp = ((unsigned)__builtin_bit_cast(unsigned short, h1) << 16)
                            | (unsigned)__builtin_bit_cast(unsigned short, h0);
                unsigned lp = ((unsigned)__builtin_bit_cast(unsigned short, l1) << 16)
                            | (unsigned)__builtin_bit_cast(unsigned short, l0);
                *(unsigned*)&Ah[row][j] = hp;
                *(unsigned*)&Al[row][j] = lp;
            }
        }
    }
    __syncthreads();

    // ---- GEMM: wave w -> z-tile (w&3), k-half (w>>2) ----
    {
        int w = tid >> 6;
        int l = tid & 63;
        int m = l & 15;                     // A row (y) / B row (z) / C col
        int g = l >> 4;                     // k-group (8 consecutive k)
        int zt = w & 3;
        int kh = w >> 2;
        v4f accHH = {0.f, 0.f, 0.f, 0.f};
        v4f accHL = {0.f, 0.f, 0.f, 0.f};
        v4f accLH = {0.f, 0.f, 0.f, 0.f};
        const __bf16* bhp = EzTh + (zt * 16 + m) * 768 + kh * 384 + g * 8;
        const __bf16* blp = EzTl + (zt * 16 + m) * 768 + kh * 384 + g * 8;
        const __bf16* ahp = &Ah[m][kh * 384 + g * 8];
        const __bf16* alp = &Al[m][kh * 384 + g * 8];
#pragma unroll 4
        for (int ks = 0; ks < 12; ++ks) {
            v8bf aH = *(const v8bf*)(ahp + ks * 32);
            v8bf aL = *(const v8bf*)(alp + ks * 32);
            v8bf bH = *(const v8bf*)(bhp + ks * 32);
            v8bf bL = *(const v8bf*)(blp + ks * 32);
            accHH = __builtin_amdgcn_mfma_f32_16x16x32_bf16(aH, bH, accHH, 0, 0, 0);
            accHL = __builtin_amdgcn_mfma_f32_16x16x32_bf16(aH, bL, accHL, 0, 0, 0);
            accLH = __builtin_amdgcn_mfma_f32_16x16x32_bf16(aL, bH, accLH, 0, 0, 0);
        }
        // C layout: col = lane&15, row = (lane>>4)*4 + reg  [m89-verified]
#pragma unroll
        for (int r = 0; r < 4; ++r) {
            float s = accHH[r] + accHL[r] + accLH[r];
            if (kh == 0) D[g * 4 + r][zt * 16 + m].x = s;
            else         D[g * 4 + r][zt * 16 + m].y = s;
        }
    }
    __syncthreads();

    // ---- forward z-FFT on the 16 lines (128 active threads) ----
    bool active = tid < 128;
    int lid = (tid >> 3) & 15, t = tid & 7;
    float2 xin[8], y[8];
    if (active) {
#pragma unroll
        for (int n2 = 0; n2 < 8; ++n2) {
            float2 v = D[lid][8 * n2 + t];
            xin[n2] = make_float2(v.x + v.y, 0.f);   // sum k-halves
        }
    }
    xf64<false>(xin, &D[lid][0], 1, t, tw, y, active);
    if (active) {
        int ybase = yq * 16 + lid;
#pragma unroll
        for (int k2 = 0; k2 < 8; ++k2) {
            int kz = t + 8 * k2;
            if (KZ_LIVE(kz))                // out-of-band planes never read
                W2[kz * 4096 + x * 64 + ybase] = y[k2];
        }
    }
}

// ---------------------------------------------------------------------------
// K2: per-kz plane (in-band kz only, 33 blocks): fwd-y, fwd-x, xHamming
// (+ DC extract + |G|^2 partial), inv-x, inv-y. 33 blocks x 512 threads.
// ---------------------------------------------------------------------------
__global__ __launch_bounds__(512) void plane_kernel(
    float2* __restrict__ W2, const float* __restrict__ ham,
    const float2* __restrict__ twg, double* __restrict__ partial)
{
    __shared__ float2 P[64][66];
    __shared__ float2 tw[64];
    __shared__ double red[8];
    int tid = threadIdx.x;
    if (tid < 64) tw[tid] = twg[tid];

    int z0 = blockIdx.x <= 16 ? blockIdx.x : blockIdx.x + 31;  // in-band kz
    const float4* src = (const float4*)(W2 + z0 * 4096);
#pragma unroll
    for (int q = 0; q < 4; ++q) {
        int i = tid + q * 512;
        float4 v = src[i];
        int e = i * 2;
        P[e >> 6][e & 63] = make_float2(v.x, v.y);
        P[e >> 6][(e & 63) + 1] = make_float2(v.z, v.w);
    }
    __syncthreads();

    int lid = tid >> 3, t = tid & 7;
    float2 xin[8], y[8];

    // forward y (lines = rows x = lid)
#pragma unroll
    for (int n2 = 0; n2 < 8; ++n2) xin[n2] = P[lid][8 * n2 + t];
    xf64<false>(xin, &P[lid][0], 1, t, tw, y, true);
    __syncthreads();
#pragma unroll
    for (int k2 = 0; k2 < 8; ++k2) P[lid][t + 8 * k2] = y[k2];
    __syncthreads();

    // forward x (lines = columns ky = lid) + Hamming
#pragma unroll
    for (int n2 = 0; n2 < 8; ++n2) xin[n2] = P[8 * n2 + t][lid];
    xf64<false>(xin, &P[0][lid], 66, t, tw, y, true);
    {
        int hyz = ((lid + 32) & 63) * 64 + ((z0 + 32) & 63);
#pragma unroll
        for (int k2 = 0; k2 < 8; ++k2) {
            int kx = t + 8 * k2;
            float h = ham[((kx + 32) & 63) * 4096 + hyz];
            y[k2].x *= h; y[k2].y *= h;
        }
    }
    // ---- Parseval partial: sum |G|^2 over this plane; grab DC coeff ----
    {
        double s2 = 0.0;
#pragma unroll
        for (int k2 = 0; k2 < 8; ++k2)
            s2 += (double)y[k2].x * y[k2].x + (double)y[k2].y * y[k2].y;
#pragma unroll
        for (int off = 32; off > 0; off >>= 1)
            s2 += __shfl_down(s2, off, 64);
        if ((tid & 63) == 0) red[tid >> 6] = s2;
        if (z0 == 0 && tid == 0)                  // kx=0, ky=0, kz=0
            partial[64] = (double)y[0].x;
    }
    __syncthreads();
#pragma unroll
    for (int k2 = 0; k2 < 8; ++k2) P[t + 8 * k2][lid] = y[k2];
    __syncthreads();
    if (tid == 0) {
        double s = 0.0;
#pragma unroll
        for (int i = 0; i < 8; ++i) s += red[i];
        partial[z0] = s;
    }

    // inverse x
#pragma unroll
    for (int n2 = 0; n2 < 8; ++n2) xin[n2] = P[8 * n2 + t][lid];
    xf64<true>(xin, &P[0][lid], 66, t, tw, y, true);
    __syncthreads();
#pragma unroll
    for (int k2 = 0; k2 < 8; ++k2) P[t + 8 * k2][lid] = y[k2];
    __syncthreads();

    // inverse y, write back
#pragma unroll
    for (int n2 = 0; n2 < 8; ++n2) xin[n2] = P[lid][8 * n2 + t];
    xf64<true>(xin, &P[lid][0], 1, t, tw, y, true);
#pragma unroll
    for (int k2 = 0; k2 < 8; ++k2)
        W2[z0 * 4096 + lid * 64 + t + 8 * k2] = y[k2];
}

// ---------------------------------------------------------------------------
// K3: inverse z-FFT (sparse in-band input) + real + scale + NORMALIZE
// (mean/std from Parseval/DC). 256 blocks x 128 threads, all threads active.
// ---------------------------------------------------------------------------
__global__ __launch_bounds__(128) void invz_norm_kernel(
    const float2* __restrict__ W2, const float2* __restrict__ twg,
    const double* __restrict__ partial, float* __restrict__ outr)
{
    __shared__ float2 ln[16][66];
    __shared__ float2 tw[64];
    __shared__ float nrm[2];
    int tid = threadIdx.x;
    if (tid < 64) {
        tw[tid] = twg[tid];
        // only in-band partial[] entries were written (rest is poison)
        double s = KZ_LIVE(tid) ? partial[tid] : 0.0;
#pragma unroll
        for (int off = 32; off > 0; off >>= 1)
            s += __shfl_down(s, off, 64);
        if (tid == 0) {
            double mean = partial[64] * (1.0 / 262144.0);
            double var = s * (1.0 / 262144.0 / 262144.0) - mean * mean;
            nrm[0] = (float)mean;
            nrm[1] = (float)(1.0 / (sqrt(var > 0.0 ? var : 0.0) + 1e-8));
        }
    }
    __syncthreads();

    int lid = tid >> 3, t = tid & 7;        // lid 0..15
    int L = blockIdx.x * 16 + lid;          // (x,y) line id
    float2 xin[8], y[8];
#pragma unroll
    for (int n2 = 0; n2 < 8; ++n2) {
        int kz = 8 * n2 + t;
        xin[n2] = KZ_LIVE(kz) ? W2[kz * 4096 + L] : make_float2(0.f, 0.f);
    }
    xf64<true>(xin, &ln[lid][0], 1, t, tw, y, true);

    float mean = nrm[0], rstd = nrm[1];
#pragma unroll
    for (int k2 = 0; k2 < 8; ++k2) {
        float v = y[k2].x * (1.0f / 262144.0f);
        outr[L * 64 + t + 8 * k2] = (v - mean) * rstd;
    }
}

// ---------------------------------------------------------------------------
extern "C" void kernel_launch(void* const* d_in, const int* in_sizes, int n_in,
                              void* d_out, int out_size, void* d_ws,
                              size_t ws_size, hipStream_t stream)
{
    const float* X   = (const float*)d_in[0];
    const float* aw  = (const float*)d_in[1];
    const float* bw  = (const float*)d_in[2];
    const float* ham = (const float*)d_in[4];
    float* out = (float*)d_out;

    char* ws = (char*)d_ws;
    float2* W2   = (float2*)(ws + WS_W);
    __bf16* EzTh = (__bf16*)(ws + WS_EZH);
    __bf16* EzTl = (__bf16*)(ws + WS_EZL);
    float2* twg  = (float2*)(ws + WS_TW);
    double* part = (double*)(ws + WS_PART);

    ez_tw_kernel<<<64, 256, 0, stream>>>(X, bw, EzTh, EzTl, twg);
    density_fftz_kernel<<<256, 512, 0, stream>>>(X, aw, bw, EzTh, EzTl, twg, W2);
    plane_kernel<<<33, 512, 0, stream>>>(W2, ham, twg, part);
    invz_norm_kernel<<<256, 128, 0, stream>>>(W2, twg, part, out);
}

// Round 9
// 24.827 us; speedup vs baseline: 5.4972x; 1.2723x over previous
//
#include <hip/hip_runtime.h>
#include <math.h>

#define NG (64*64*64)

typedef __bf16 v8bf __attribute__((ext_vector_type(8)));
typedef float  v4f  __attribute__((ext_vector_type(4)));

// ---- workspace layout (bytes) ----
#define WS_W    0                        // float2[NG]  2 MiB   (layout W2[kz][x][y])
#define WS_PART (2*1024*1024)            // double[65]: [0..63] plane |G|^2, [64] DC

// Band limit: hamming == 0 exactly for per-axis |k| > 16 (cutoff 0.5 = 16/32).
// In DFT index terms: k in {0..16} U {48..63} survives; 17..47 is dead.
#define K_LIVE(k) ((k) <= 16 || (k) >= 48)

// ---------------------------------------------------------------------------
// Fast radix-2 8-point FFT, natural order in/out. CONJ=true -> inverse sign.
// ---------------------------------------------------------------------------
__device__ __forceinline__ float2 cadd(float2 a, float2 b) {
    return make_float2(a.x + b.x, a.y + b.y);
}
__device__ __forceinline__ float2 csub(float2 a, float2 b) {
    return make_float2(a.x - b.x, a.y - b.y);
}
template <bool CONJ>
__device__ __forceinline__ float2 mulmi(float2 a) {   // *(-i) fwd, *(+i) inv
    return CONJ ? make_float2(-a.y, a.x) : make_float2(a.y, -a.x);
}

template <bool CONJ>
__device__ __forceinline__ void fft8(const float2 x[8], float2 y[8])
{
    const float r = 0.70710678118654752f;
    float2 ee0 = cadd(x[0], x[4]), ee1 = csub(x[0], x[4]);
    float2 eo0 = cadd(x[2], x[6]), eo1 = csub(x[2], x[6]);
    float2 E0 = cadd(ee0, eo0), E2 = csub(ee0, eo0);
    float2 me = mulmi<CONJ>(eo1);
    float2 E1 = cadd(ee1, me), E3 = csub(ee1, me);
    float2 oe0 = cadd(x[1], x[5]), oe1 = csub(x[1], x[5]);
    float2 oo0 = cadd(x[3], x[7]), oo1 = csub(x[3], x[7]);
    float2 O0 = cadd(oe0, oo0), O2 = csub(oe0, oo0);
    float2 mo = mulmi<CONJ>(oo1);
    float2 O1 = cadd(oe1, mo), O3 = csub(oe1, mo);
    float2 W1O1 = CONJ ? make_float2(r * (O1.x - O1.y), r * (O1.x + O1.y))
                       : make_float2(r * (O1.x + O1.y), r * (O1.y - O1.x));
    float2 W2O2 = mulmi<CONJ>(O2);
    float2 W3O3 = CONJ ? make_float2(-r * (O3.x + O3.y), r * (O3.x - O3.y))
                       : make_float2(r * (O3.y - O3.x), -r * (O3.x + O3.y));
    y[0] = cadd(E0, O0);   y[4] = csub(E0, O0);
    y[1] = cadd(E1, W1O1); y[5] = csub(E1, W1O1);
    y[2] = cadd(E2, W2O2); y[6] = csub(E2, W2O2);
    y[3] = cadd(E3, W3O3); y[7] = csub(E3, W3O3);
}

// 64-pt transform, radix 8x8, 8 threads/line. Input xin[n2] = element 8*n2+t.
// L[(...)*es] is the per-line exchange buffer (each thread rewrites the slots
// it read -> no pre-barrier). Internal block barrier; ALL threads must call
// (inactive skip compute). Output y[k2] = element t+8*k2.
template <bool CONJ>
__device__ __forceinline__ void xf64(const float2 xin[8], float2* L, int es,
                                     int t, const float2* tw, float2 y[8],
                                     bool active)
{
    float2 b[8];
    if (active) {
        fft8<CONJ>(xin, b);
#pragma unroll
        for (int k1 = 0; k1 < 8; ++k1) {
            float2 wv = tw[(t * k1) & 63];
            float ws = CONJ ? -wv.y : wv.y;
            float tr = b[k1].x * wv.x - b[k1].y * ws;
            float ti = b[k1].x * ws + b[k1].y * wv.x;
            b[k1] = make_float2(tr, ti);
        }
#pragma unroll
        for (int k1 = 0; k1 < 8; ++k1)
            L[(k1 * 8 + t) * es] = b[k1];
    }
    __syncthreads();
    if (active) {
        float2 a[8];
#pragma unroll
        for (int n1 = 0; n1 < 8; ++n1) a[n1] = L[(t * 8 + n1) * es];
        fft8<CONJ>(a, y);
    }
}

// Per-block twiddle table (forward sign), written by tid<64.
__device__ __forceinline__ void make_tw(float2* tw, int tid)
{
    if (tid < 64) {
        float ang = -6.28318530717958647692f * (float)tid / 64.0f;
        float s, c;
        sincosf(ang, &s, &c);
        tw[tid] = make_float2(c, s);
    }
}

// ---------------------------------------------------------------------------
// K1: density (A in LDS, B = Ez computed IN-REGISTER per lane, MFMA,
// K-split over 8 waves) + fwd z-FFT. Block = (x, y-quarter), 512 thr, 256 blk.
//   A[y][j] = aw[j]*exp(bw[j]*(dx^2+dy^2))  (hi/lo bf16 in LDS)
//   B[j][z] = exp(bw[j]*dz^2)               (hi/lo bf16, per-lane registers)
//   3 MFMAs per k-step (Ah*Bh + Ah*Bl + Al*Bh) recover f32 accuracy.
// Writes only in-band kz planes of W2.
// ---------------------------------------------------------------------------
__global__ __launch_bounds__(512) void density_fftz_kernel(
    const float* __restrict__ X, const float* __restrict__ aw,
    const float* __restrict__ bw, float2* __restrict__ W2)
{
    __shared__ __align__(16) __bf16 Ah[16][776];
    __shared__ __align__(16) __bf16 Al[16][776];
    __shared__ float2 D[16][66];
    __shared__ float2 tw[64];

    int tid = threadIdx.x;
    make_tw(tw, tid);

    int blk = blockIdx.x;
    int x  = blk >> 2;
    int yq = blk & 3;
    float px = 0.5f * (float)x;

    // ---- build A in-register: thread -> (row, 4 atoms x 6 terms) ----
    {
        int row = tid >> 5;                 // 0..15
        int a0  = (tid & 31) * 4;           // 4 atoms -> 24 consecutive j
        float py = 0.5f * (float)(yq * 16 + row);
#pragma unroll
        for (int ai = 0; ai < 4; ++ai) {
            int a = a0 + ai;
            float dxa = px - X[3 * a + 0];
            float dya = py - X[3 * a + 1];
            float d2 = dxa * dxa + dya * dya;
            int jb = a * 6;
#pragma unroll
            for (int p = 0; p < 3; ++p) {   // 3 packed pairs
                int j = jb + 2 * p;
                float e0 = aw[j] * __expf(bw[j] * d2);
                float e1 = aw[j + 1] * __expf(bw[j + 1] * d2);
                __bf16 h0 = (__bf16)e0, h1 = (__bf16)e1;
                __bf16 l0 = (__bf16)(e0 - (float)h0);
                __bf16 l1 = (__bf16)(e1 - (float)h1);
                unsigned hp = ((unsigned)__builtin_bit_cast(unsigned short, h1) << 16)
                            | (unsigned)__builtin_bit_cast(unsigned short, h0);
                unsigned lp = ((unsigned)__builtin_bit_cast(unsigned short, l1) << 16)
                            | (unsigned)__builtin_bit_cast(unsigned short, l0);
                *(unsigned*)&Ah[row][j] = hp;
                *(unsigned*)&Al[row][j] = lp;
            }
        }
    }
    __syncthreads();

    // ---- GEMM: wave w -> z-tile (w&3), k-half (w>>2); B in-register ----
    {
        int w = tid >> 6;
        int l = tid & 63;
        int m = l & 15;                     // A row (y) / B col (z) / C col
        int g = l >> 4;                     // k-group (8 consecutive k)
        int zt = w & 3;
        int kh = w >> 2;
        float pz = 0.5f * (float)(zt * 16 + m);
        int jb0 = kh * 384 + g * 8;
        v4f accHH = {0.f, 0.f, 0.f, 0.f};
        v4f accHL = {0.f, 0.f, 0.f, 0.f};
        v4f accLH = {0.f, 0.f, 0.f, 0.f};
        const __bf16* ahp = &Ah[m][jb0];
        const __bf16* alp = &Al[m][jb0];
#pragma unroll 2
        for (int ks = 0; ks < 12; ++ks) {
            v8bf aH = *(const v8bf*)(ahp + ks * 32);
            v8bf aL = *(const v8bf*)(alp + ks * 32);
            v8bf bH, bL;
#pragma unroll
            for (int p = 0; p < 4; ++p) {
                int j = jb0 + ks * 32 + 2 * p;       // even-aligned pair
                float2 bwp = *(const float2*)(bw + j);
                int a0 = j / 6, a1 = (j + 1) / 6;
                float dz0 = pz - X[3 * a0 + 2];
                float dz1 = pz - X[3 * a1 + 2];
                float e0 = __expf(bwp.x * dz0 * dz0);
                float e1 = __expf(bwp.y * dz1 * dz1);
                __bf16 h0 = (__bf16)e0, h1 = (__bf16)e1;
                bH[2 * p]     = h0;
                bH[2 * p + 1] = h1;
                bL[2 * p]     = (__bf16)(e0 - (float)h0);
                bL[2 * p + 1] = (__bf16)(e1 - (float)h1);
            }
            accHH = __builtin_amdgcn_mfma_f32_16x16x32_bf16(aH, bH, accHH, 0, 0, 0);
            accHL = __builtin_amdgcn_mfma_f32_16x16x32_bf16(aH, bL, accHL, 0, 0, 0);
            accLH = __builtin_amdgcn_mfma_f32_16x16x32_bf16(aL, bH, accLH, 0, 0, 0);
        }
        // C layout: col = lane&15, row = (lane>>4)*4 + reg  [m89-verified]
#pragma unroll
        for (int r = 0; r < 4; ++r) {
            float s = accHH[r] + accHL[r] + accLH[r];
            if (kh == 0) D[g * 4 + r][zt * 16 + m].x = s;
            else         D[g * 4 + r][zt * 16 + m].y = s;
        }
    }
    __syncthreads();

    // ---- forward z-FFT on the 16 lines (128 active threads) ----
    bool active = tid < 128;
    int lid = (tid >> 3) & 15, t = tid & 7;
    float2 xin[8], y[8];
    if (active) {
#pragma unroll
        for (int n2 = 0; n2 < 8; ++n2) {
            float2 v = D[lid][8 * n2 + t];
            xin[n2] = make_float2(v.x + v.y, 0.f);   // sum k-halves
        }
    }
    xf64<false>(xin, &D[lid][0], 1, t, tw, y, active);
    if (active) {
        int ybase = yq * 16 + lid;
#pragma unroll
        for (int k2 = 0; k2 < 8; ++k2) {
            int kz = t + 8 * k2;
            if (K_LIVE(kz))                 // out-of-band planes never read
                W2[kz * 4096 + x * 64 + ybase] = y[k2];
        }
    }
}

// ---------------------------------------------------------------------------
// K2: per-kz plane (in-band kz only, 33 blocks): fwd-y (64 lines), fwd-x
// (33 in-band ky lines only), xHamming (+ DC + |G|^2 partial; out-of-band
// ky columns zeroed), inv-x (33 lines), inv-y (64 lines). 33 x 512 threads.
// ---------------------------------------------------------------------------
__global__ __launch_bounds__(512) void plane_kernel(
    float2* __restrict__ W2, const float* __restrict__ ham,
    double* __restrict__ partial)
{
    __shared__ float2 P[64][66];
    __shared__ float2 tw[64];
    __shared__ double red[8];
    int tid = threadIdx.x;
    make_tw(tw, tid);

    int z0 = blockIdx.x <= 16 ? blockIdx.x : blockIdx.x + 31;  // in-band kz
    const float4* src = (const float4*)(W2 + z0 * 4096);
#pragma unroll
    for (int q = 0; q < 4; ++q) {
        int i = tid + q * 512;
        float4 v = src[i];
        int e = i * 2;
        P[e >> 6][e & 63] = make_float2(v.x, v.y);
        P[e >> 6][(e & 63) + 1] = make_float2(v.z, v.w);
    }
    __syncthreads();

    int lid = tid >> 3, t = tid & 7;
    float2 xin[8], y[8];

    // forward y (lines = rows x = lid; all 64)
#pragma unroll
    for (int n2 = 0; n2 < 8; ++n2) xin[n2] = P[lid][8 * n2 + t];
    xf64<false>(xin, &P[lid][0], 1, t, tw, y, true);
    __syncthreads();
#pragma unroll
    for (int k2 = 0; k2 < 8; ++k2) P[lid][t + 8 * k2] = y[k2];
    __syncthreads();

    // forward x: only in-band ky lines (H == 0 kills the rest)
    bool kyLive = K_LIVE(lid);
#pragma unroll
    for (int n2 = 0; n2 < 8; ++n2) xin[n2] = P[8 * n2 + t][lid];
    xf64<false>(xin, &P[0][lid], 66, t, tw, y, kyLive);
    if (kyLive) {
        int hyz = ((lid + 32) & 63) * 64 + ((z0 + 32) & 63);
#pragma unroll
        for (int k2 = 0; k2 < 8; ++k2) {
            int kx = t + 8 * k2;
            float h = ham[((kx + 32) & 63) * 4096 + hyz];
            y[k2].x *= h; y[k2].y *= h;
        }
    }
    // ---- Parseval partial (in-band lines only) + DC coefficient ----
    {
        double s2 = 0.0;
        if (kyLive) {
#pragma unroll
            for (int k2 = 0; k2 < 8; ++k2)
                s2 += (double)y[k2].x * y[k2].x + (double)y[k2].y * y[k2].y;
        }
#pragma unroll
        for (int off = 32; off > 0; off >>= 1)
            s2 += __shfl_down(s2, off, 64);
        if ((tid & 63) == 0) red[tid >> 6] = s2;
        if (z0 == 0 && tid == 0)                  // kx=0, ky=0, kz=0
            partial[64] = (double)y[0].x;
    }
    __syncthreads();
#pragma unroll
    for (int k2 = 0; k2 < 8; ++k2)                // zero dead-ky columns
        P[t + 8 * k2][lid] = kyLive ? y[k2] : make_float2(0.f, 0.f);
    __syncthreads();
    if (tid == 0) {
        double s = 0.0;
#pragma unroll
        for (int i = 0; i < 8; ++i) s += red[i];
        partial[z0] = s;
    }

    // inverse x: only in-band ky lines (others are all-zero -> stay zero)
#pragma unroll
    for (int n2 = 0; n2 < 8; ++n2) xin[n2] = P[8 * n2 + t][lid];
    xf64<true>(xin, &P[0][lid], 66, t, tw, y, kyLive);
    __syncthreads();
    if (kyLive) {
#pragma unroll
        for (int k2 = 0; k2 < 8; ++k2) P[t + 8 * k2][lid] = y[k2];
    }
    __syncthreads();

    // inverse y (all 64 x rows; dead-ky inputs are zeros), write back
#pragma unroll
    for (int n2 = 0; n2 < 8; ++n2) xin[n2] = P[lid][8 * n2 + t];
    xf64<true>(xin, &P[lid][0], 1, t, tw, y, true);
#pragma unroll
    for (int k2 = 0; k2 < 8; ++k2)
        W2[z0 * 4096 + lid * 64 + t + 8 * k2] = y[k2];
}

// ---------------------------------------------------------------------------
// K3: inverse z-FFT (sparse in-band input) + real + scale + NORMALIZE
// (mean/std from Parseval/DC). 256 blocks x 128 threads, all threads active.
// ---------------------------------------------------------------------------
__global__ __launch_bounds__(128) void invz_norm_kernel(
    const float2* __restrict__ W2, const double* __restrict__ partial,
    float* __restrict__ outr)
{
    __shared__ float2 ln[16][66];
    __shared__ float2 tw[64];
    __shared__ float nrm[2];
    int tid = threadIdx.x;
    make_tw(tw, tid);
    if (tid < 64) {
        // only in-band partial[] entries were written (rest is poison)
        double s = K_LIVE(tid) ? partial[tid] : 0.0;
#pragma unroll
        for (int off = 32; off > 0; off >>= 1)
            s += __shfl_down(s, off, 64);
        if (tid == 0) {
            double mean = partial[64] * (1.0 / 262144.0);
            double var = s * (1.0 / 262144.0 / 262144.0) - mean * mean;
            nrm[0] = (float)mean;
            nrm[1] = (float)(1.0 / (sqrt(var > 0.0 ? var : 0.0) + 1e-8));
        }
    }
    __syncthreads();

    int lid = tid >> 3, t = tid & 7;        // lid 0..15
    int L = blockIdx.x * 16 + lid;          // (x,y) line id
    float2 xin[8], y[8];
#pragma unroll
    for (int n2 = 0; n2 < 8; ++n2) {
        int kz = 8 * n2 + t;
        xin[n2] = K_LIVE(kz) ? W2[kz * 4096 + L] : make_float2(0.f, 0.f);
    }
    xf64<true>(xin, &ln[lid][0], 1, t, tw, y, true);

    float mean = nrm[0], rstd = nrm[1];
#pragma unroll
    for (int k2 = 0; k2 < 8; ++k2) {
        float v = y[k2].x * (1.0f / 262144.0f);
        outr[L * 64 + t + 8 * k2] = (v - mean) * rstd;
    }
}

// ---------------------------------------------------------------------------
extern "C" void kernel_launch(void* const* d_in, const int* in_sizes, int n_in,
                              void* d_out, int out_size, void* d_ws,
                              size_t ws_size, hipStream_t stream)
{
    const float* X   = (const float*)d_in[0];
    const float* aw  = (const float*)d_in[1];
    const float* bw  = (const float*)d_in[2];
    const float* ham = (const float*)d_in[4];
    float* out = (float*)d_out;

    char* ws = (char*)d_ws;
    float2* W2   = (float2*)(ws + WS_W);
    double* part = (double*)(ws + WS_PART);

    density_fftz_kernel<<<256, 512, 0, stream>>>(X, aw, bw, W2);
    plane_kernel<<<33, 512, 0, stream>>>(W2, ham, part);
    invz_norm_kernel<<<256, 128, 0, stream>>>(W2, part, out);
}